// Round 1
// baseline (20544.313 us; speedup 1.0000x reference)
//
#include <hip/hip_runtime.h>
#include <math.h>

#define BB 64
#define TT 2048
#define RR 256
#define NT 5

// One workgroup per batch element. 1024 threads = 4 row-groups (q) x 256 columns (s).
// Thread (q,s) accumulates the partial feedback for output column s over rows
// r in [64q, 64q+64) for all 5 taps. History lives in d_out itself.
__global__ __launch_bounds__(1024)
void reservoir_step_kernel(const float* __restrict__ x,
                           const float* __restrict__ W_in,
                           const float* __restrict__ W_fb,
                           const float* __restrict__ tapw,
                           const float* __restrict__ bias,
                           float* __restrict__ out)
{
    const int b   = blockIdx.x;
    const int tid = threadIdx.x;
    const int q   = tid >> 8;    // 0..3 row group
    const int s   = tid & 255;   // output column

    __shared__ float xs[TT];        // 8 KB: whole input sequence for this batch
    __shared__ float hd[NT][RR];    // 5 KB: tap_w-scaled delayed states for step t
    __shared__ float part[4][RR];   // 4 KB: per-row-group partial sums

    // Stage the input sequence (INPUT_DIM == 1).
    for (int i = tid; i < TT; i += 1024) xs[i] = x[b * TT + i];

    // softmax(tap_weights) — tiny, computed redundantly per thread.
    float w0 = tapw[0], w1 = tapw[1], w2 = tapw[2], w3 = tapw[3], w4 = tapw[4];
    float mx = fmaxf(fmaxf(fmaxf(w0, w1), fmaxf(w2, w3)), w4);
    float e0 = expf(w0 - mx), e1 = expf(w1 - mx), e2 = expf(w2 - mx),
          e3 = expf(w3 - mx), e4 = expf(w4 - mx);
    float inv = 1.0f / (e0 + e1 + e2 + e3 + e4);
    const float tw0 = e0 * inv, tw1 = e1 * inv, tw2 = e2 * inv,
                tw3 = e3 * inv, tw4 = e4 * inv;

    const float win_s  = W_in[s];   // INPUT_DIM == 1
    const float bias_s = bias[s];
    float hprev = 0.0f;             // h_{t-1}[s], per-thread register (redundant over q)

    // W_fb layout [k][r][s]; this thread reads rows q*64 .. q*64+63, column s.
    const float* Wth  = W_fb + (q * 64) * RR + s;
    float* outb = out + (size_t)b * TT * RR;

    __syncthreads();  // xs ready

    for (int t = 0; t < TT; ++t) {
        // ---- Phase A: stage scaled delayed states into LDS ----
        // tap delays: 1, 4, 24, 96, 168. Tap d=1 is hprev (register).
        if (q == 0) {
            hd[0][s] = tw0 * hprev;
        } else if (q == 1) {
            hd[1][s] = (t >= 4)  ? tw1 * outb[(t - 4)  * RR + s] : 0.0f;
        } else if (q == 2) {
            hd[2][s] = (t >= 24) ? tw2 * outb[(t - 24) * RR + s] : 0.0f;
        } else {
            hd[3][s] = (t >= 96) ? tw3 * outb[(t - 96) * RR + s] : 0.0f;
            hd[4][s] = (t >= 168)? tw4 * outb[(t - 168)* RR + s] : 0.0f;
        }
        __syncthreads();

        // ---- Phase B: partial feedback for column s over this q's 64 rows ----
        float acc = 0.0f;
#pragma unroll
        for (int k = 0; k < NT; ++k) {
            const float4* h4 = (const float4*)(&hd[k][q * 64]);
            const float*  Wp = Wth + k * (RR * RR);
#pragma unroll 8
            for (int r4 = 0; r4 < 16; ++r4) {
                float4 h = h4[r4];
                acc = fmaf(h.x, Wp[0],       acc);
                acc = fmaf(h.y, Wp[RR],      acc);
                acc = fmaf(h.z, Wp[2 * RR],  acc);
                acc = fmaf(h.w, Wp[3 * RR],  acc);
                Wp += 4 * RR;
            }
        }
        part[q][s] = acc;
        __syncthreads();

        // ---- Phase C: leaky update (redundant across q; q0 writes out) ----
        float fb = part[0][s] + part[1][s] + part[2][s] + part[3][s];
        float h  = 0.9f * hprev + 0.1f * tanhf(xs[t] * win_s + fb + bias_s);
        hprev = h;
        if (q == 0) outb[t * RR + s] = h;
    }
}

extern "C" void kernel_launch(void* const* d_in, const int* in_sizes, int n_in,
                              void* d_out, int out_size, void* d_ws, size_t ws_size,
                              hipStream_t stream) {
    const float* x     = (const float*)d_in[0];   // (64, 2048, 1)
    const float* W_in  = (const float*)d_in[1];   // (256, 1)
    const float* W_fb  = (const float*)d_in[2];   // (5, 256, 256)
    const float* tapw  = (const float*)d_in[3];   // (5,)
    const float* bias  = (const float*)d_in[4];   // (256,)
    float* out = (float*)d_out;                   // (64, 2048, 256)

    reservoir_step_kernel<<<BB, 1024, 0, stream>>>(x, W_in, W_fb, tapw, bias, out);
}